// Round 1
// 85.265 us; speedup vs baseline: 1.1453x; 1.1453x over previous
//
#include <hip/hip_runtime.h>
#include <math.h>

#define BB 2
#define FF 32
#define NN 1024
#define HH 64
#define TI 8   // i-rows per block in edge kernel

typedef _Float16 h2 __attribute__((ext_vector_type(2)));

// ---------------------------------------------------------------------------
// Kernel 1: hi2[b,n,h]  = fp16( |W2[h]| * sum_f emb[b,f,n]*W1[h,f] )
//           hjb2[b,n,h] = fp16( |W2[h]| * (sum_f emb[b,f,n]*W1[h,F+f] + b1[h]) )
//           wpk[h]      = fp16( copysign(log2e, W2[h]) )
// Folding |W2| in keeps fp16 magnitudes small (better rounding) and lets the
// edge kernel's dot2 multiply by +-log2e only (sigmoid exp2 conversion free).
// One thread per (b,n,h); h fastest for coalesced writes.
// ---------------------------------------------------------------------------
__global__ __launch_bounds__(256) void prep_kernel(
    const float* __restrict__ emb,   // (B,F,N)
    const float* __restrict__ W1,    // (H, 2F)
    const float* __restrict__ b1,    // (H)
    const float* __restrict__ W2,    // (H)
    _Float16* __restrict__ hi2,      // (B,N,H)
    _Float16* __restrict__ hjb2,     // (B,N,H)
    _Float16* __restrict__ wpk)      // (H)
{
    int t = blockIdx.x * 256 + threadIdx.x;   // t in [0, B*N*H)
    int h = t & (HH - 1);
    int n = (t >> 6) & (NN - 1);
    int b = t >> 16;                          // 6 + 10 bits

    const float* e = emb + (size_t)b * FF * NN + n;  // stride NN over f
    const float* w = W1 + (size_t)h * (2 * FF);

    float si = 0.f, sj = 0.f;
#pragma unroll
    for (int f = 0; f < FF; ++f) {
        float ev = e[(size_t)f * NN];
        si = fmaf(ev, w[f], si);
        sj = fmaf(ev, w[FF + f], sj);
    }
    float aw = fabsf(W2[h]);
    hi2[t]  = (_Float16)(si * aw);
    hjb2[t] = (_Float16)((sj + b1[h]) * aw);
    if (t < HH) wpk[t] = (_Float16)copysignf(1.44269504f, W2[t]);
}

// ---------------------------------------------------------------------------
// Kernel 2: out[b,i,j] = sigmoid( sum_h relu(hi+hj)*W2[h] + b2 )
//         = rcp(1 + exp2( -( sum_h dot2( relu_pk(hi2+hjb2), +-log2e ) + b2*log2e ) ))
// Packed fp16: v_pk_add_f16 + v_pk_max_f16 + v_dot2_f32_f16 = 3 instr / 2 h
// (vs 6 fp32 instr / 2 h). Accumulation stays fp32 inside dot2.
// Thread owns one j (hjb row = 32 h2 in 16 VGPRs), loops TI values of i.
// ---------------------------------------------------------------------------
__global__ __launch_bounds__(256) void edge_kernel(
    const _Float16* __restrict__ hi2,    // (B,N,H)
    const _Float16* __restrict__ hjb2,   // (B,N,H)
    const _Float16* __restrict__ wpk,    // (H)
    const float* __restrict__ b2,        // (1)
    float* __restrict__ out)             // (B,N,N)
{
    const int j  = blockIdx.x * 256 + threadIdx.x;
    const int i0 = blockIdx.y * TI;
    const int b  = blockIdx.z;

    // this thread's hjb row: 64 halves = 128 B, 8x dwordx4
    float4 hjv[8];
    const float4* hp = (const float4*)(hjb2 + ((size_t)b * NN + j) * HH);
#pragma unroll
    for (int k = 0; k < 8; ++k) hjv[k] = hp[k];
    const h2* hj = (const h2*)hjv;

    // +-log2e sign vector (wave-uniform)
    float4 wv[8];
    const float4* wp = (const float4*)wpk;
#pragma unroll
    for (int k = 0; k < 8; ++k) wv[k] = wp[k];
    const h2* wh = (const h2*)wv;

    const float accInit = b2[0] * 1.44269504f;   // b2 * log2e folded into acc
    const _Float16* hib = hi2 + ((size_t)b * NN + i0) * HH;
    float* op = out + ((size_t)b * NN + i0) * NN + j;

    const h2 hz = { _Float16(0), _Float16(0) };

#pragma unroll
    for (int ii = 0; ii < TI; ++ii) {
        // wave-uniform hi row for this i: 128 B
        float4 hiv[8];
        const float4* hr = (const float4*)(hib + (size_t)ii * HH);
#pragma unroll
        for (int k = 0; k < 8; ++k) hiv[k] = hr[k];
        const h2* hih = (const h2*)hiv;

        float a0 = accInit, a1 = 0.f, a2 = 0.f, a3 = 0.f;
#pragma unroll
        for (int k = 0; k < 8; ++k) {
            h2 t0 = __builtin_elementwise_max(hih[4 * k + 0] + hj[4 * k + 0], hz);
            h2 t1 = __builtin_elementwise_max(hih[4 * k + 1] + hj[4 * k + 1], hz);
            h2 t2 = __builtin_elementwise_max(hih[4 * k + 2] + hj[4 * k + 2], hz);
            h2 t3 = __builtin_elementwise_max(hih[4 * k + 3] + hj[4 * k + 3], hz);
            a0 = __builtin_amdgcn_fdot2(t0, wh[4 * k + 0], a0, false);
            a1 = __builtin_amdgcn_fdot2(t1, wh[4 * k + 1], a1, false);
            a2 = __builtin_amdgcn_fdot2(t2, wh[4 * k + 2], a2, false);
            a3 = __builtin_amdgcn_fdot2(t3, wh[4 * k + 3], a3, false);
        }
        float s = (a0 + a1) + (a2 + a3);
        op[(size_t)ii * NN] = __builtin_amdgcn_rcpf(1.f + __builtin_amdgcn_exp2f(-s));
    }
}

// ---------------------------------------------------------------------------
extern "C" void kernel_launch(void* const* d_in, const int* in_sizes, int n_in,
                              void* d_out, int out_size, void* d_ws, size_t ws_size,
                              hipStream_t stream) {
    // inputs: 0 adj_in (unused), 1 emb_in, 2 layer (unused), 3 W1, 4 b1, 5 W2, 6 b2
    const float* emb = (const float*)d_in[1];
    const float* W1  = (const float*)d_in[3];
    const float* b1  = (const float*)d_in[4];
    const float* W2  = (const float*)d_in[5];
    const float* b2  = (const float*)d_in[6];
    float* out = (float*)d_out;

    _Float16* hi2  = (_Float16*)d_ws;                       // B*N*H halves (256 KB)
    _Float16* hjb2 = hi2 + (size_t)BB * NN * HH;            // B*N*H halves
    _Float16* wpk  = hjb2 + (size_t)BB * NN * HH;           // H halves

    prep_kernel<<<(BB * NN * HH) / 256, 256, 0, stream>>>(emb, W1, b1, W2, hi2, hjb2, wpk);

    dim3 grid(NN / 256, NN / TI, BB);
    edge_kernel<<<grid, 256, 0, stream>>>(hi2, hjb2, wpk, b2, out);
}